// Round 15
// baseline (2394.072 us; speedup 1.0000x reference)
//
#include <hip/hip_runtime.h>
#include <stdint.h>
#include <stddef.h>

#define BB 8
#define LL 1024
#define CC 512
#define KHn 4
#define HIDn 64
#define NLAYER 2
#define MM (BB*LL)

typedef __attribute__((ext_vector_type(4))) float f32x4;
typedef __attribute__((ext_vector_type(8))) short s16x8;
typedef __attribute__((ext_vector_type(4))) short s16x4;

__device__ __forceinline__ short f2bf(float x){
  union { float f; uint32_t u; } v; v.f = x;
  uint32_t r = v.u + 0x7FFFu + ((v.u >> 16) & 1u);
  return (short)(r >> 16);
}

// bf16 strip scratch in graphs-L0 zero triangle (rows<512, cols>=512): strips 0..4095 (val1)
__device__ __forceinline__ short* strip_ptr(char* base, size_t f){
  size_t beta = f << 1;
  size_t strip = beta >> 11;
  return (short*)(base + ((strip >> 9) << 22) + ((strip & 511) << 12) + 2048 + (beta & 2047));
}
// fp32 strips 4096..4351: L1 partial row sums (131072 floats: [mk*4+g][1024])
__device__ __forceinline__ float* sums_strip(char* base, size_t i){
  size_t strip = 4096 + (i >> 9);
  return (float*)(base + ((strip >> 9) << 22) + ((strip & 511) << 12) + 2048) + (i & 511);
}

// ---------------- BN fold ----------------
__global__ void k_scaleshift(const float* b1,const float* g1,const float* be1,const float* m1,const float* v1,
                             const float* b2,const float* g2,const float* be2,const float* m2,const float* v2,
                             float* sc1, float* sh1, float* sc2, float* sh2){
  int c = blockIdx.x*256 + threadIdx.x;
  if (c < CC){
    float s = g1[c]*rsqrtf(v1[c]+1e-5f); sc1[c]=s; sh1[c]=(b1[c]-m1[c])*s+be1[c];
  } else if (c < 2*CC){
    int d = c - CC;
    float s = g2[d]*rsqrtf(v2[d]+1e-5f); sc2[d]=s; sh2[d]=(b2[d]-m2[d])*s+be2[d];
  }
}

// conv weights [O][C][3] -> fp32 [3][O][C]
__global__ void k_convwT(const float* __restrict__ wk, const float* __restrict__ wq,
                         float* __restrict__ wTk, float* __restrict__ wTq){
  int idx = blockIdx.x*256 + threadIdx.x;          // over 3*CC*CC
  int seg = idx / (CC*CC);
  int o   = (idx / CC) % CC;
  int c   = idx % CC;
  size_t src = ((size_t)o*CC + c)*3 + seg;
  wTk[idx] = wk[src];
  wTq[idx] = wq[src];
}

__global__ void k_cast(const float* __restrict__ in, short* __restrict__ out, int n){
  int i = blockIdx.x*256 + threadIdx.x;
  if (i < n) out[i] = f2bf(in[i]);
}

// ---------------- zero upper-triangle region of one graphs layer ----------------
__global__ void k_zfill(float* __restrict__ gout){
  const int qt = blockIdx.x, kh = blockIdx.y, b = blockIdx.z;
  const int c0 = (qt + 1) << 6;
  const int ncol = LL - c0;
  if (ncol <= 0) return;
  float* base = gout + (size_t)(b*KHn + kh)*LL*LL + ((size_t)(qt << 6))*LL;
  const int nc4 = ncol >> 2;
  const int tot = 64 * nc4;
  f32x4 z; z[0]=0.f; z[1]=0.f; z[2]=0.f; z[3]=0.f;
  for (int i = threadIdx.x; i < tot; i += 256){
    int r = i / nc4, c = (i % nc4) << 2;
    *(f32x4*)&base[(size_t)r*LL + c0 + c] = z;
  }
}

// ---------------- zero partial row-sum arrays (arena fp32 + strips), 131072 each ----------------
__global__ void k_zsum(float* __restrict__ partial0, char* sbase){
  int i = blockIdx.x*256 + threadIdx.x;   // over 131072
  partial0[i] = 0.f;
  *sums_strip(sbase, i) = 0.f;
}

// ---------------- conv tower fp32, transposed LDS ----------------
__global__ __launch_bounds__(256,2)
void k_convT(const float* __restrict__ X, const float* __restrict__ Wt,
             const float* __restrict__ sc, const float* __restrict__ sh,
             float* __restrict__ O)
{
  __shared__ float As[64][68];   // [k][m]
  __shared__ float Bs[64][68];   // [k][n]
  const int tid = threadIdx.x, ty = tid >> 4, tx = tid & 15;
  const int m0 = blockIdx.x << 6, n0 = blockIdx.y << 6;
  const int mlow = m0 & (LL-1);
  float accs[4][4] = {};
  for (int seg = 0; seg < 3; ++seg){
    const int shift = seg - 2;
    for (int k0 = 0; k0 < CC; k0 += 64){
      __syncthreads();
      #pragma unroll
      for (int it = 0; it < 4; ++it){
        int idx = tid + (it << 8);
        int r = idx >> 4, c4 = (idx & 15) << 2;
        f32x4 av; av[0]=0.f; av[1]=0.f; av[2]=0.f; av[3]=0.f;
        if (mlow + r + shift >= 0) av = *(const f32x4*)&X[(size_t)(m0 + r + shift)*CC + k0 + c4];
        As[c4+0][r]=av[0]; As[c4+1][r]=av[1]; As[c4+2][r]=av[2]; As[c4+3][r]=av[3];
        f32x4 bv = *(const f32x4*)&Wt[((size_t)seg*CC + n0 + r)*CC + k0 + c4];
        Bs[c4+0][r]=bv[0]; Bs[c4+1][r]=bv[1]; Bs[c4+2][r]=bv[2]; Bs[c4+3][r]=bv[3];
      }
      __syncthreads();
      #pragma unroll
      for (int k = 0; k < 64; ++k){
        f32x4 qa = *(const f32x4*)&As[k][ty<<2];
        f32x4 kb = *(const f32x4*)&Bs[k][tx<<2];
        #pragma unroll
        for (int i=0;i<4;++i)
          #pragma unroll
          for (int j=0;j<4;++j)
            accs[i][j] += qa[i]*kb[j];
      }
    }
  }
  const int c0 = n0 + (tx<<2);
  f32x4 s4 = *(const f32x4*)&sc[c0];
  f32x4 h4 = *(const f32x4*)&sh[c0];
  #pragma unroll
  for (int i=0;i<4;++i){
    int gr = m0 + (ty<<2) + i;
    f32x4 v;
    #pragma unroll
    for (int j=0;j<4;++j) v[j] = fmaxf(accs[i][j]*s4[j] + h4[j], 0.f);
    *(f32x4*)&O[(size_t)gr*CC + c0] = v;
  }
}

// ---------------- NT linear fp32, transposed LDS; PACK=1 -> per-head layout [mk][L][64] ----------------
template<int PACK>
__global__ __launch_bounds__(256,2)
void k_linT(const float* __restrict__ A, int lda,
            const float* __restrict__ B, int ldb, int K,
            const float* __restrict__ bias,
            float* __restrict__ O, int ldo)
{
  __shared__ float As[64][68];
  __shared__ float Bs[64][68];
  const int tid = threadIdx.x, ty = tid >> 4, tx = tid & 15;
  const int m0 = blockIdx.x << 6, n0 = blockIdx.y << 6;
  float accs[4][4] = {};
  for (int k0 = 0; k0 < K; k0 += 64){
    __syncthreads();
    #pragma unroll
    for (int it = 0; it < 4; ++it){
      int idx = tid + (it << 8);
      int r = idx >> 4, c4 = (idx & 15) << 2;
      f32x4 av = *(const f32x4*)&A[(size_t)(m0 + r)*lda + k0 + c4];
      As[c4+0][r]=av[0]; As[c4+1][r]=av[1]; As[c4+2][r]=av[2]; As[c4+3][r]=av[3];
      f32x4 bv = *(const f32x4*)&B[(size_t)(n0 + r)*ldb + k0 + c4];
      Bs[c4+0][r]=bv[0]; Bs[c4+1][r]=bv[1]; Bs[c4+2][r]=bv[2]; Bs[c4+3][r]=bv[3];
    }
    __syncthreads();
    #pragma unroll
    for (int k = 0; k < 64; ++k){
      f32x4 qa = *(const f32x4*)&As[k][ty<<2];
      f32x4 kb = *(const f32x4*)&Bs[k][tx<<2];
      #pragma unroll
      for (int i=0;i<4;++i)
        #pragma unroll
        for (int j=0;j<4;++j)
          accs[i][j] += qa[i]*kb[j];
    }
  }
  const int c0 = n0 + (tx<<2);
  f32x4 b4 = *(const f32x4*)&bias[c0];
  #pragma unroll
  for (int i=0;i<4;++i){
    int gr = m0 + (ty<<2) + i;
    f32x4 v;
    #pragma unroll
    for (int j=0;j<4;++j) v[j] = accs[i][j] + b4[j];
    if (PACK){
      int bb = gr >> 10, l = gr & (LL-1);
      int kh = c0 >> 6, h = c0 & 63;
      *(f32x4*)&O[(((size_t)(bb*KHn + kh))*LL + l)*HIDn + h] = v;
    } else {
      *(f32x4*)&O[(size_t)gr*ldo + c0] = v;
    }
  }
}

// ---------------- 4-wide scores groups: block = 64 q-rows x up-to-4 s-subtiles ----------------
// q/k in PACKED per-head layout [mk][1024][64]. partial slot g = subtile-group index (0..3).
template<int SSTRIP>
__global__ __launch_bounds__(256,2)
void k_stile(const float* __restrict__ qp, const float* __restrict__ kp,
             float* __restrict__ gout, float* __restrict__ partial, char* sbase)
{
  __shared__ float Qs[64][68];   // [h][q]
  __shared__ float Ks[64][68];   // [h][s]
  const int tid = threadIdx.x, ty = tid >> 4, tx = tid & 15;
  const int t = blockIdx.x, kh = blockIdx.y, b = blockIdx.z;
  // decode t (0..39) -> (qt, g): ng(qt) = (qt+4)>>2
  int qt = 0, g = 0, acc = 0;
  for (int q = 0; q < 16; ++q){
    int ng = (q + 4) >> 2;
    if (t < acc + ng){ qt = q; g = t - acc; break; }
    acc += ng;
  }
  const int q0 = qt << 6;
  const int mk = b*KHn + kh;
  const float* qb = qp + (size_t)mk*LL*HIDn;
  const float* kb = kp + (size_t)mk*LL*HIDn;

  // stage Q tile: fully contiguous 16 KB
  #pragma unroll
  for (int it = 0; it < 4; ++it){
    int idx = tid + (it << 8);
    int r = idx >> 4, c4 = (idx & 15) << 2;
    f32x4 av = *(const f32x4*)&qb[(size_t)(q0 + r)*HIDn + c4];
    Qs[c4+0][r]=av[0]; Qs[c4+1][r]=av[1]; Qs[c4+2][r]=av[2]; Qs[c4+3][r]=av[3];
  }

  float* grow = gout + (size_t)mk*LL*LL;
  float rsum[4] = {};
  const int stEnd = (qt < (g<<2)+3) ? qt : ((g<<2)+3);
  for (int st = g<<2; st <= stEnd; ++st){
    const int s0 = st << 6;
    __syncthreads();
    #pragma unroll
    for (int it = 0; it < 4; ++it){
      int idx = tid + (it << 8);
      int r = idx >> 4, c4 = (idx & 15) << 2;
      f32x4 bv = *(const f32x4*)&kb[(size_t)(s0 + r)*HIDn + c4];
      Ks[c4+0][r]=bv[0]; Ks[c4+1][r]=bv[1]; Ks[c4+2][r]=bv[2]; Ks[c4+3][r]=bv[3];
    }
    __syncthreads();
    float accs[4][4] = {};
    #pragma unroll
    for (int k = 0; k < 64; ++k){
      f32x4 qa = *(const f32x4*)&Qs[k][ty<<2];
      f32x4 kv4 = *(const f32x4*)&Ks[k][tx<<2];
      #pragma unroll
      for (int i=0;i<4;++i)
        #pragma unroll
        for (int j=0;j<4;++j)
          accs[i][j] += qa[i]*kv4[j];
    }
    #pragma unroll
    for (int i=0;i<4;++i){
      const int q = q0 + (ty<<2) + i;
      f32x4 v;
      #pragma unroll
      for (int j=0;j<4;++j){
        const int s = s0 + (tx<<2) + j;
        float tt = (s < q) ? fmaxf(accs[i][j], 0.f) : 0.f;
        v[j] = tt*tt;
        rsum[i] += v[j];
      }
      *(f32x4*)&grow[(size_t)q*LL + s0 + (tx<<2)] = v;
    }
  }
  #pragma unroll
  for (int i=0;i<4;++i){
    float r = rsum[i];
    r += __shfl_xor(r, 1); r += __shfl_xor(r, 2);
    r += __shfl_xor(r, 4); r += __shfl_xor(r, 8);
    if (tx == 0){
      size_t idx = (((size_t)mk*4 + g) << 10) + q0 + (ty<<2) + i;
      if (SSTRIP) *sums_strip(sbase, idx) = r;
      else        partial[idx] = r;
    }
  }
}

// ---------------- MFMA GEMM (v-proj): val = bf16(A_f32 @ B_bf16^T + bias) ----------------
template<int SOUT>
__global__ __launch_bounds__(256,2)
void k_gemm(const float* __restrict__ Af, int lda,
            const short* __restrict__ Bm, int ldb, int K,
            const float* __restrict__ bias,
            short* __restrict__ Obf, int ldo, char* gbase)
{
  __shared__ short As[128][72];
  __shared__ short Bs[128][72];
  const int tid = threadIdx.x, lane = tid & 63, wid = tid >> 6;
  const int wm = wid >> 1, wn = wid & 1;
  const int m0 = blockIdx.x << 7, n0 = blockIdx.y << 7;
  const int lr = lane & 15, lk = (lane >> 4) << 3;

  f32x4 acc[4][4];
  #pragma unroll
  for (int m=0;m<4;++m)
    #pragma unroll
    for (int n=0;n<4;++n){ acc[m][n][0]=0.f; acc[m][n][1]=0.f; acc[m][n][2]=0.f; acc[m][n][3]=0.f; }

  for (int k0 = 0; k0 < K; k0 += 64){
    __syncthreads();
    #pragma unroll
    for (int it=0; it<4; ++it){
      int idx8 = tid + (it<<8);
      int r = idx8 >> 3, cv = (idx8 & 7) << 3;
      f32x4 v0 = *(const f32x4*)&Af[(size_t)(m0+r)*lda + k0 + cv];
      f32x4 v1 = *(const f32x4*)&Af[(size_t)(m0+r)*lda + k0 + cv + 4];
      s16x8 h;
      h[0]=f2bf(v0[0]); h[1]=f2bf(v0[1]); h[2]=f2bf(v0[2]); h[3]=f2bf(v0[3]);
      h[4]=f2bf(v1[0]); h[5]=f2bf(v1[1]); h[6]=f2bf(v1[2]); h[7]=f2bf(v1[3]);
      *(s16x8*)&As[r][cv] = h;
      *(s16x8*)&Bs[r][cv] = *(const s16x8*)&Bm[(size_t)(n0+r)*ldb + k0 + cv];
    }
    __syncthreads();
    #pragma unroll
    for (int kj=0; kj<2; ++kj){
      const int ko = (kj<<5) + lk;
      s16x8 av[4], bv[4];
      #pragma unroll
      for (int m=0;m<4;++m) av[m] = *(const s16x8*)&As[(wm<<6) + (m<<4) + lr][ko];
      #pragma unroll
      for (int n=0;n<4;++n) bv[n] = *(const s16x8*)&Bs[(wn<<6) + (n<<4) + lr][ko];
      #pragma unroll
      for (int m=0;m<4;++m)
        #pragma unroll
        for (int n=0;n<4;++n)
          acc[m][n] = __builtin_amdgcn_mfma_f32_16x16x32_bf16(av[m], bv[n], acc[m][n], 0,0,0);
    }
  }
  const int rr = (lane >> 4) << 2;
  #pragma unroll
  for (int m=0;m<4;++m)
    #pragma unroll
    for (int n=0;n<4;++n){
      const int gc = n0 + (wn<<6) + (n<<4) + lr;
      float e0 = bias[gc];
      #pragma unroll
      for (int r=0;r<4;++r){
        const int gr = m0 + (wm<<6) + (m<<4) + rr + r;
        short val = f2bf(acc[m][n][r] + e0);
        if (SOUT) *strip_ptr(gbase, (size_t)gr*ldo + gc) = val;
        else      Obf[(size_t)gr*ldo + gc] = val;
      }
    }
}

// ---------------- MFMA PV: fused 4-way sum-reduce + normalize + write-back ----------------
template<int VS>
__global__ __launch_bounds__(256,2)
void k_pv(float* __restrict__ att, const short* __restrict__ valbf, char* vbase,
          const float* __restrict__ partial,
          const float* __restrict__ prevf, float* __restrict__ outs)
{
  __shared__ short As[128][72];
  __shared__ short Bs[128][72];
  __shared__ float rinv_s[128];
  const int tid = threadIdx.x, lane = tid & 63, wid = tid >> 6;
  const int wm = wid >> 1, wn = wid & 1;
  const int qt = blockIdx.x, kh = blockIdx.y, b = blockIdx.z;
  const int qbase = qt << 7;
  const int lr = lane & 15, lk = (lane >> 4) << 3, rr2 = (lane >> 4) << 2;
  const int mk = b*KHn + kh;
  float* attb = att + ((size_t)mk)*LL*LL;

  if (tid < 128){
    int q = qbase + tid;
    float s = 0.f;
    #pragma unroll
    for (int g = 0; g < 4; ++g){
      size_t idx = (((size_t)mk*4 + g) << 10) + q;
      s += VS ? *sums_strip(vbase, idx) : partial[idx];
    }
    rinv_s[tid] = 1.0f/(s + 1e-16f);
  }

  f32x4 acc[4][4];
  #pragma unroll
  for (int m=0;m<4;++m)
    #pragma unroll
    for (int n=0;n<4;++n){ acc[m][n][0]=0.f; acc[m][n][1]=0.f; acc[m][n][2]=0.f; acc[m][n][3]=0.f; }

  const int nt = (qbase >> 6) + 2;
  for (int st=0; st<nt; ++st){
    const int sb = st << 6;
    __syncthreads();
    #pragma unroll
    for (int it=0; it<8; ++it){
      int idx4 = tid + (it<<8);
      int r = idx4 >> 4, cv = (idx4 & 15) << 2;
      float* src = &attb[(size_t)(qbase + r)*LL + sb + cv];
      f32x4 v = *(f32x4*)src;
      float ri = rinv_s[r];
      v[0]*=ri; v[1]*=ri; v[2]*=ri; v[3]*=ri;
      *(f32x4*)src = v;
      s16x4 h; h[0]=f2bf(v[0]); h[1]=f2bf(v[1]); h[2]=f2bf(v[2]); h[3]=f2bf(v[3]);
      *(s16x4*)&As[r][cv] = h;
    }
    #pragma unroll
    for (int it=0; it<32; ++it){
      int idx = tid + (it<<8);
      int sl = idx >> 7, d = idx & 127;
      size_t f = (size_t)(b*LL + sb + sl)*CC + kh*128 + d;
      Bs[d][sl] = VS ? *strip_ptr(vbase, f) : valbf[f];
    }
    __syncthreads();
    #pragma unroll
    for (int kj=0;kj<2;++kj){
      int ko = (kj<<5) + lk;
      s16x8 av[4], bv[4];
      #pragma unroll
      for (int m=0;m<4;++m) av[m] = *(const s16x8*)&As[(wm<<6)+(m<<4)+lr][ko];
      #pragma unroll
      for (int n=0;n<4;++n) bv[n] = *(const s16x8*)&Bs[(wn<<6)+(n<<4)+lr][ko];
      #pragma unroll
      for (int m=0;m<4;++m)
        #pragma unroll
        for (int n=0;n<4;++n)
          acc[m][n] = __builtin_amdgcn_mfma_f32_16x16x32_bf16(av[m], bv[n], acc[m][n], 0,0,0);
    }
  }
  #pragma unroll
  for (int m=0;m<4;++m)
    #pragma unroll
    for (int n=0;n<4;++n)
      #pragma unroll
      for (int r=0;r<4;++r){
        const int R = b*LL + qbase + (wm<<6) + (m<<4) + rr2 + r;
        const int gc = kh*128 + (wn<<6) + (n<<4) + lr;
        size_t o = (size_t)R*CC + gc;
        outs[o] = prevf[o] + acc[m][n][r];
      }
}

// restore borrowed strips (8192 x 2KB) to zero
__global__ void k_restore(char* gbase){
  size_t strip = blockIdx.x;
  char* p = gbase + ((strip >> 9) << 22) + ((strip & 511) << 12) + 2048;
  f32x4 z; z[0]=0.f; z[1]=0.f; z[2]=0.f; z[3]=0.f;
  ((f32x4*)p)[threadIdx.x] = z;
}

extern "C" void kernel_launch(void* const* d_in, const int* in_sizes, int n_in,
                              void* d_out, int out_size, void* d_ws, size_t ws_size,
                              hipStream_t stream)
{
  (void)in_sizes; (void)n_in; (void)out_size; (void)d_ws; (void)ws_size;
  const float* input  = (const float*)d_in[0];
  const float* ck_w   = (const float*)d_in[1];
  const float* ck_b   = (const float*)d_in[2];
  const float* ck_g   = (const float*)d_in[3];
  const float* ck_be  = (const float*)d_in[4];
  const float* ck_m   = (const float*)d_in[5];
  const float* ck_v   = (const float*)d_in[6];
  const float* cq_w   = (const float*)d_in[7];
  const float* cq_b   = (const float*)d_in[8];
  const float* cq_g   = (const float*)d_in[9];
  const float* cq_be  = (const float*)d_in[10];
  const float* cq_m   = (const float*)d_in[11];
  const float* cq_v   = (const float*)d_in[12];
  const float* qW     = (const float*)d_in[13];
  const float* qb     = (const float*)d_in[14];
  const float* kW     = (const float*)d_in[15];
  const float* kb     = (const float*)d_in[16];
  const float* vW     = (const float*)d_in[17];
  const float* vb     = (const float*)d_in[18];

  float* graphs   = (float*)d_out;
  float* g1       = graphs + (size_t)BB*KHn*LL*LL;
  float* outsBase = graphs + (size_t)NLAYER*BB*KHn*LL*LL;
  float* outs0 = outsBase;
  float* outs1 = outsBase + (size_t)MM*CC;

  // scratch arena in g1 (dead before zfill/stile L1 write g1)
  char* RA = (char*)g1;
  float* key_out  = (float*)(RA + 0);          // 16.78 MB
  float* qry_out  = (float*)(RA + 16777216);   // 16.78 MB
  float* q0v      = (float*)(RA + 33554432);   //  8.39 MB (packed per-head)
  float* k0v      = (float*)(RA + 41943040);   //  8.39 MB (packed per-head)
  short* val0_bf  = (short*)(RA + 50331648);   //  8.39 MB
  short* vW_bf    = (short*)(RA + 58720256);   //  1.05 MB
  float* wTk      = (float*)(RA + 59768832);   //  3.15 MB
  float* wTq      = (float*)(RA + 62914560);   //  3.15 MB
  float* partial0 = (float*)(RA + 66060288);   //  0.52 MB (131072 floats)
  float* ck_sc    = (float*)(RA + 66584576);
  float* ck_sh    = (float*)(RA + 66586624);
  float* cq_sc    = (float*)(RA + 66588672);
  float* cq_sh    = (float*)(RA + 66590720);
  // layer-1 q/k (packed) in outs1 region (dead before pv L1 writes it)
  float* q1v = outs1;
  float* k1v = outs1 + (size_t)MM*KHn*HIDn;
  char* gL0 = (char*)d_out;

  const int NT4 = 40;   // 4-wide groups per (b,kh)

  k_scaleshift<<<4, 256, 0, stream>>>(ck_b, ck_g, ck_be, ck_m, ck_v,
                                      cq_b, cq_g, cq_be, cq_m, cq_v,
                                      ck_sc, ck_sh, cq_sc, cq_sh);
  k_convwT<<<(3*CC*CC)/256, 256, 0, stream>>>(ck_w, cq_w, wTk, wTq);
  k_cast<<<(NLAYER*CC*CC)/256, 256, 0, stream>>>(vW, vW_bf, NLAYER*CC*CC);

  // L0 upper-triangle zeros FIRST (before any strips are populated)
  k_zfill<<<dim3(LL/64, KHn, BB), 256, 0, stream>>>(graphs);
  // zero partial row-sum arrays (arena + strips)
  k_zsum<<<512, 256, 0, stream>>>(partial0, gL0);

  k_convT<<<dim3(MM/64, CC/64), 256, 0, stream>>>(input, wTk, ck_sc, ck_sh, key_out);
  k_convT<<<dim3(MM/64, CC/64), 256, 0, stream>>>(input, wTq, cq_sc, cq_sh, qry_out);

  // ---- layer 0 ----
  k_linT<1><<<dim3(MM/64, (KHn*HIDn)/64), 256, 0, stream>>>(qry_out, CC, qW, CC, CC,
                                                            qb, q0v, KHn*HIDn);
  k_linT<1><<<dim3(MM/64, (KHn*HIDn)/64), 256, 0, stream>>>(key_out, CC, kW, CC, CC,
                                                            kb, k0v, KHn*HIDn);
  k_gemm<0><<<dim3(MM/128, CC/128), 256, 0, stream>>>(input, CC, vW_bf, CC, CC,
                                                      vb, val0_bf, CC, nullptr);
  k_stile<0><<<dim3(NT4, KHn, BB), 256, 0, stream>>>(q0v, k0v, graphs, partial0, nullptr);
  k_pv<0><<<dim3(LL/128, KHn, BB), 256, 0, stream>>>(graphs, val0_bf, gL0, partial0,
                                                     input, outs0);

  // ---- layer 1 ----
  k_gemm<1><<<dim3(MM/128, CC/128), 256, 0, stream>>>(outs0, CC, vW_bf + (size_t)CC*CC, CC, CC,
                                                      vb + CC, nullptr, CC, gL0);
  k_linT<1><<<dim3(MM/64, (KHn*HIDn)/64), 256, 0, stream>>>(qry_out, CC,
                                                            qW + (size_t)KHn*HIDn*CC, CC, CC,
                                                            qb + KHn*HIDn, q1v, KHn*HIDn);
  k_linT<1><<<dim3(MM/64, (KHn*HIDn)/64), 256, 0, stream>>>(key_out, CC,
                                                            kW + (size_t)KHn*HIDn*CC, CC, CC,
                                                            kb + KHn*HIDn, k1v, KHn*HIDn);
  // arena fully dead now -> zero L1 upper triangle, then compute L1 tiles
  k_zfill<<<dim3(LL/64, KHn, BB), 256, 0, stream>>>(g1);
  k_stile<1><<<dim3(NT4, KHn, BB), 256, 0, stream>>>(q1v, k1v, g1, nullptr, gL0);
  k_pv<1><<<dim3(LL/128, KHn, BB), 256, 0, stream>>>(g1, nullptr, gL0, nullptr,
                                                     outs0, outs1);
  k_restore<<<8192, 128, 0, stream>>>(gL0);
}

// Round 16
// 1286.173 us; speedup vs baseline: 1.8614x; 1.8614x over previous
//
#include <hip/hip_runtime.h>
#include <stdint.h>
#include <stddef.h>

#define BB 8
#define LL 1024
#define CC 512
#define KHn 4
#define HIDn 64
#define NLAYER 2
#define MM (BB*LL)

typedef __attribute__((ext_vector_type(4))) float f32x4;
typedef __attribute__((ext_vector_type(8))) short s16x8;
typedef __attribute__((ext_vector_type(4))) short s16x4;

__device__ __forceinline__ short f2bf(float x){
  union { float f; uint32_t u; } v; v.f = x;
  uint32_t r = v.u + 0x7FFFu + ((v.u >> 16) & 1u);
  return (short)(r >> 16);
}

// bf16 strip scratch in graphs-L0 zero triangle (rows<512, cols>=512): strips 0..4095 (val1)
__device__ __forceinline__ short* strip_ptr(char* base, size_t f){
  size_t beta = f << 1;
  size_t strip = beta >> 11;
  return (short*)(base + ((strip >> 9) << 22) + ((strip & 511) << 12) + 2048 + (beta & 2047));
}
// fp32 strips 4096..4223: L1 partial row sums (65536 floats: [(mk*2+half)][1024])
__device__ __forceinline__ float* sums_strip(char* base, size_t i){
  size_t strip = 4096 + (i >> 9);
  return (float*)(base + ((strip >> 9) << 22) + ((strip & 511) << 12) + 2048) + (i & 511);
}

// ---------------- BN fold ----------------
__global__ void k_scaleshift(const float* b1,const float* g1,const float* be1,const float* m1,const float* v1,
                             const float* b2,const float* g2,const float* be2,const float* m2,const float* v2,
                             float* sc1, float* sh1, float* sc2, float* sh2){
  int c = blockIdx.x*256 + threadIdx.x;
  if (c < CC){
    float s = g1[c]*rsqrtf(v1[c]+1e-5f); sc1[c]=s; sh1[c]=(b1[c]-m1[c])*s+be1[c];
  } else if (c < 2*CC){
    int d = c - CC;
    float s = g2[d]*rsqrtf(v2[d]+1e-5f); sc2[d]=s; sh2[d]=(b2[d]-m2[d])*s+be2[d];
  }
}

// conv weights [O][C][3] -> fp32 [3][O][C]
__global__ void k_convwT(const float* __restrict__ wk, const float* __restrict__ wq,
                         float* __restrict__ wTk, float* __restrict__ wTq){
  int idx = blockIdx.x*256 + threadIdx.x;          // over 3*CC*CC
  int seg = idx / (CC*CC);
  int o   = (idx / CC) % CC;
  int c   = idx % CC;
  size_t src = ((size_t)o*CC + c)*3 + seg;
  wTk[idx] = wk[src];
  wTq[idx] = wq[src];
}

__global__ void k_cast(const float* __restrict__ in, short* __restrict__ out, int n){
  int i = blockIdx.x*256 + threadIdx.x;
  if (i < n) out[i] = f2bf(in[i]);
}

// ---------------- conv tower fp32, transposed LDS ----------------
__global__ __launch_bounds__(256,2)
void k_convT(const float* __restrict__ X, const float* __restrict__ Wt,
             const float* __restrict__ sc, const float* __restrict__ sh,
             float* __restrict__ O)
{
  __shared__ float As[64][68];   // [k][m]
  __shared__ float Bs[64][68];   // [k][n]
  const int tid = threadIdx.x, ty = tid >> 4, tx = tid & 15;
  const int m0 = blockIdx.x << 6, n0 = blockIdx.y << 6;
  const int mlow = m0 & (LL-1);
  float accs[4][4] = {};
  for (int seg = 0; seg < 3; ++seg){
    const int shift = seg - 2;
    for (int k0 = 0; k0 < CC; k0 += 64){
      __syncthreads();
      #pragma unroll
      for (int it = 0; it < 4; ++it){
        int idx = tid + (it << 8);
        int r = idx >> 4, c4 = (idx & 15) << 2;
        f32x4 av; av[0]=0.f; av[1]=0.f; av[2]=0.f; av[3]=0.f;
        if (mlow + r + shift >= 0) av = *(const f32x4*)&X[(size_t)(m0 + r + shift)*CC + k0 + c4];
        As[c4+0][r]=av[0]; As[c4+1][r]=av[1]; As[c4+2][r]=av[2]; As[c4+3][r]=av[3];
        f32x4 bv = *(const f32x4*)&Wt[((size_t)seg*CC + n0 + r)*CC + k0 + c4];
        Bs[c4+0][r]=bv[0]; Bs[c4+1][r]=bv[1]; Bs[c4+2][r]=bv[2]; Bs[c4+3][r]=bv[3];
      }
      __syncthreads();
      #pragma unroll
      for (int k = 0; k < 64; ++k){
        f32x4 qa = *(const f32x4*)&As[k][ty<<2];
        f32x4 kb = *(const f32x4*)&Bs[k][tx<<2];
        #pragma unroll
        for (int i=0;i<4;++i)
          #pragma unroll
          for (int j=0;j<4;++j)
            accs[i][j] += qa[i]*kb[j];
      }
    }
  }
  const int c0 = n0 + (tx<<2);
  f32x4 s4 = *(const f32x4*)&sc[c0];
  f32x4 h4 = *(const f32x4*)&sh[c0];
  #pragma unroll
  for (int i=0;i<4;++i){
    int gr = m0 + (ty<<2) + i;
    f32x4 v;
    #pragma unroll
    for (int j=0;j<4;++j) v[j] = fmaxf(accs[i][j]*s4[j] + h4[j], 0.f);
    *(f32x4*)&O[(size_t)gr*CC + c0] = v;
  }
}

// ---------------- NT linear fp32, transposed LDS; PACK=1 -> per-head layout [mk][L][64] ----------------
template<int PACK>
__global__ __launch_bounds__(256,2)
void k_linT(const float* __restrict__ A, int lda,
            const float* __restrict__ B, int ldb, int K,
            const float* __restrict__ bias,
            float* __restrict__ O, int ldo)
{
  __shared__ float As[64][68];
  __shared__ float Bs[64][68];
  const int tid = threadIdx.x, ty = tid >> 4, tx = tid & 15;
  const int m0 = blockIdx.x << 6, n0 = blockIdx.y << 6;
  float accs[4][4] = {};
  for (int k0 = 0; k0 < K; k0 += 64){
    __syncthreads();
    #pragma unroll
    for (int it = 0; it < 4; ++it){
      int idx = tid + (it << 8);
      int r = idx >> 4, c4 = (idx & 15) << 2;
      f32x4 av = *(const f32x4*)&A[(size_t)(m0 + r)*lda + k0 + c4];
      As[c4+0][r]=av[0]; As[c4+1][r]=av[1]; As[c4+2][r]=av[2]; As[c4+3][r]=av[3];
      f32x4 bv = *(const f32x4*)&B[(size_t)(n0 + r)*ldb + k0 + c4];
      Bs[c4+0][r]=bv[0]; Bs[c4+1][r]=bv[1]; Bs[c4+2][r]=bv[2]; Bs[c4+3][r]=bv[3];
    }
    __syncthreads();
    #pragma unroll
    for (int k = 0; k < 64; ++k){
      f32x4 qa = *(const f32x4*)&As[k][ty<<2];
      f32x4 kb = *(const f32x4*)&Bs[k][tx<<2];
      #pragma unroll
      for (int i=0;i<4;++i)
        #pragma unroll
        for (int j=0;j<4;++j)
          accs[i][j] += qa[i]*kb[j];
    }
  }
  const int c0 = n0 + (tx<<2);
  f32x4 b4 = *(const f32x4*)&bias[c0];
  #pragma unroll
  for (int i=0;i<4;++i){
    int gr = m0 + (ty<<2) + i;
    f32x4 v;
    #pragma unroll
    for (int j=0;j<4;++j) v[j] = accs[i][j] + b4[j];
    if (PACK){
      int bb = gr >> 10, l = gr & (LL-1);
      int kh = c0 >> 6, h = c0 & 63;
      *(f32x4*)&O[(((size_t)(bb*KHn + kh))*LL + l)*HIDn + h] = v;
    } else {
      *(f32x4*)&O[(size_t)gr*ldo + c0] = v;
    }
  }
}

// ---------------- scores: block = 16 q-rows x 512 s-cols; granule-dense row writes ----------------
// Writes unnormalized relu(qk)^2*mask for ALL (q,s) it owns (incl. zeros for s>=q).
// q/k packed per-head [mk][1024][64]. partial[(mk*2+half)*1024 + q] written exactly once.
template<int SSTRIP>
__global__ __launch_bounds__(256,2)
void k_stile(const float* __restrict__ qp, const float* __restrict__ kp,
             float* __restrict__ gout, float* __restrict__ partial, char* sbase)
{
  __shared__ float Qs[64][20];   // [h][row 0..15]
  __shared__ float Ks[64][64];   // [h][s-local]; bank: (h*64+s)%32 = s%32, 2-way free
  const int tid = threadIdx.x, lane = tid & 63, w = tid >> 6;
  const int band = blockIdx.x >> 1, half = blockIdx.x & 1;
  const int kh = blockIdx.y, b = blockIdx.z;
  const int q0 = band << 4;          // 16 rows
  const int s0 = half << 9;          // 512 cols
  const int mk = b*KHn + kh;
  float* grow = gout + (size_t)mk*LL*LL;

  const bool compute = (s0 < q0 + 15);
  float acc[4][8];
  #pragma unroll
  for (int i=0;i<4;++i)
    #pragma unroll
    for (int j=0;j<8;++j) acc[i][j] = 0.f;

  if (compute){
    const float* qb = qp + (size_t)mk*LL*HIDn;
    const float* kb = kp + (size_t)mk*LL*HIDn;
    // stage Q band: 16 rows x 64 h, transposed
    {
      int row = tid >> 4, c4 = (tid & 15) << 2;
      f32x4 av = *(const f32x4*)&qb[(size_t)(q0 + row)*HIDn + c4];
      Qs[c4+0][row]=av[0]; Qs[c4+1][row]=av[1]; Qs[c4+2][row]=av[2]; Qs[c4+3][row]=av[3];
    }
    for (int j = 0; j < 8; ++j){
      __syncthreads();
      {
        int idx = tid;
        int r = idx >> 4, c4 = (idx & 15) << 2;   // r 0..15 per pass, 4 passes
        #pragma unroll
        for (int it = 0; it < 4; ++it){
          int rr = r + (it << 4);
          f32x4 bv = *(const f32x4*)&kb[(size_t)(s0 + (j<<6) + rr)*HIDn + c4];
          Ks[c4+0][rr]=bv[0]; Ks[c4+1][rr]=bv[1]; Ks[c4+2][rr]=bv[2]; Ks[c4+3][rr]=bv[3];
        }
      }
      __syncthreads();
      #pragma unroll
      for (int h = 0; h < 64; ++h){
        float kv = Ks[h][lane];
        #pragma unroll
        for (int i=0;i<4;++i)
          acc[i][j] += Qs[h][(w<<2)+i] * kv;
      }
    }
  }
  // write phase: per row, 8 back-to-back 256B stores = dense 2KB granules
  #pragma unroll
  for (int i=0;i<4;++i){
    const int q = q0 + (w<<2) + i;
    float psum = 0.f;
    float* rw = &grow[(size_t)q*LL + s0];
    #pragma unroll
    for (int j=0;j<8;++j){
      const int s = s0 + (j<<6) + lane;
      float tt = (compute && s < q) ? fmaxf(acc[i][j], 0.f) : 0.f;
      float v = tt*tt;
      psum += v;
      rw[(j<<6) + lane] = v;
    }
    psum += __shfl_xor(psum, 1);  psum += __shfl_xor(psum, 2);
    psum += __shfl_xor(psum, 4);  psum += __shfl_xor(psum, 8);
    psum += __shfl_xor(psum, 16); psum += __shfl_xor(psum, 32);
    if (lane == 0){
      size_t idx = (((size_t)mk*2 + half) << 10) + q;
      if (SSTRIP) *sums_strip(sbase, idx) = psum;
      else        partial[idx] = psum;
    }
  }
}

// ---------------- MFMA GEMM (v-proj): val = bf16(A_f32 @ B_bf16^T + bias) ----------------
template<int SOUT>
__global__ __launch_bounds__(256,2)
void k_gemm(const float* __restrict__ Af, int lda,
            const short* __restrict__ Bm, int ldb, int K,
            const float* __restrict__ bias,
            short* __restrict__ Obf, int ldo, char* gbase)
{
  __shared__ short As[128][72];
  __shared__ short Bs[128][72];
  const int tid = threadIdx.x, lane = tid & 63, wid = tid >> 6;
  const int wm = wid >> 1, wn = wid & 1;
  const int m0 = blockIdx.x << 7, n0 = blockIdx.y << 7;
  const int lr = lane & 15, lk = (lane >> 4) << 3;

  f32x4 acc[4][4];
  #pragma unroll
  for (int m=0;m<4;++m)
    #pragma unroll
    for (int n=0;n<4;++n){ acc[m][n][0]=0.f; acc[m][n][1]=0.f; acc[m][n][2]=0.f; acc[m][n][3]=0.f; }

  for (int k0 = 0; k0 < K; k0 += 64){
    __syncthreads();
    #pragma unroll
    for (int it=0; it<4; ++it){
      int idx8 = tid + (it<<8);
      int r = idx8 >> 3, cv = (idx8 & 7) << 3;
      f32x4 v0 = *(const f32x4*)&Af[(size_t)(m0+r)*lda + k0 + cv];
      f32x4 v1 = *(const f32x4*)&Af[(size_t)(m0+r)*lda + k0 + cv + 4];
      s16x8 h;
      h[0]=f2bf(v0[0]); h[1]=f2bf(v0[1]); h[2]=f2bf(v0[2]); h[3]=f2bf(v0[3]);
      h[4]=f2bf(v1[0]); h[5]=f2bf(v1[1]); h[6]=f2bf(v1[2]); h[7]=f2bf(v1[3]);
      *(s16x8*)&As[r][cv] = h;
      *(s16x8*)&Bs[r][cv] = *(const s16x8*)&Bm[(size_t)(n0+r)*ldb + k0 + cv];
    }
    __syncthreads();
    #pragma unroll
    for (int kj=0; kj<2; ++kj){
      const int ko = (kj<<5) + lk;
      s16x8 av[4], bv[4];
      #pragma unroll
      for (int m=0;m<4;++m) av[m] = *(const s16x8*)&As[(wm<<6) + (m<<4) + lr][ko];
      #pragma unroll
      for (int n=0;n<4;++n) bv[n] = *(const s16x8*)&Bs[(wn<<6) + (n<<4) + lr][ko];
      #pragma unroll
      for (int m=0;m<4;++m)
        #pragma unroll
        for (int n=0;n<4;++n)
          acc[m][n] = __builtin_amdgcn_mfma_f32_16x16x32_bf16(av[m], bv[n], acc[m][n], 0,0,0);
    }
  }
  const int rr = (lane >> 4) << 2;
  #pragma unroll
  for (int m=0;m<4;++m)
    #pragma unroll
    for (int n=0;n<4;++n){
      const int gc = n0 + (wn<<6) + (n<<4) + lr;
      float e0 = bias[gc];
      #pragma unroll
      for (int r=0;r<4;++r){
        const int gr = m0 + (wm<<6) + (m<<4) + rr + r;
        short val = f2bf(acc[m][n][r] + e0);
        if (SOUT) *strip_ptr(gbase, (size_t)gr*ldo + gc) = val;
        else      Obf[(size_t)gr*ldo + gc] = val;
      }
    }
}

// ---------------- MFMA PV: fused 2-way sum-reduce + normalize + write-back ----------------
template<int VS>
__global__ __launch_bounds__(256,2)
void k_pv(float* __restrict__ att, const short* __restrict__ valbf, char* vbase,
          const float* __restrict__ partial,
          const float* __restrict__ prevf, float* __restrict__ outs)
{
  __shared__ short As[128][72];
  __shared__ short Bs[128][72];
  __shared__ float rinv_s[128];
  const int tid = threadIdx.x, lane = tid & 63, wid = tid >> 6;
  const int wm = wid >> 1, wn = wid & 1;
  const int qt = blockIdx.x, kh = blockIdx.y, b = blockIdx.z;
  const int qbase = qt << 7;
  const int lr = lane & 15, lk = (lane >> 4) << 3, rr2 = (lane >> 4) << 2;
  const int mk = b*KHn + kh;
  float* attb = att + ((size_t)mk)*LL*LL;

  if (tid < 128){
    int q = qbase + tid;
    float s = 0.f;
    #pragma unroll
    for (int g = 0; g < 2; ++g){
      size_t idx = (((size_t)mk*2 + g) << 10) + q;
      s += VS ? *sums_strip(vbase, idx) : partial[idx];
    }
    rinv_s[tid] = 1.0f/(s + 1e-16f);
  }

  f32x4 acc[4][4];
  #pragma unroll
  for (int m=0;m<4;++m)
    #pragma unroll
    for (int n=0;n<4;++n){ acc[m][n][0]=0.f; acc[m][n][1]=0.f; acc[m][n][2]=0.f; acc[m][n][3]=0.f; }

  const int nt = (qbase >> 6) + 2;
  for (int st=0; st<nt; ++st){
    const int sb = st << 6;
    __syncthreads();
    #pragma unroll
    for (int it=0; it<8; ++it){
      int idx4 = tid + (it<<8);
      int r = idx4 >> 4, cv = (idx4 & 15) << 2;
      float* src = &attb[(size_t)(qbase + r)*LL + sb + cv];
      f32x4 v = *(f32x4*)src;
      float ri = rinv_s[r];
      v[0]*=ri; v[1]*=ri; v[2]*=ri; v[3]*=ri;
      *(f32x4*)src = v;
      s16x4 h; h[0]=f2bf(v[0]); h[1]=f2bf(v[1]); h[2]=f2bf(v[2]); h[3]=f2bf(v[3]);
      *(s16x4*)&As[r][cv] = h;
    }
    #pragma unroll
    for (int it=0; it<32; ++it){
      int idx = tid + (it<<8);
      int sl = idx >> 7, d = idx & 127;
      size_t f = (size_t)(b*LL + sb + sl)*CC + kh*128 + d;
      Bs[d][sl] = VS ? *strip_ptr(vbase, f) : valbf[f];
    }
    __syncthreads();
    #pragma unroll
    for (int kj=0;kj<2;++kj){
      int ko = (kj<<5) + lk;
      s16x8 av[4], bv[4];
      #pragma unroll
      for (int m=0;m<4;++m) av[m] = *(const s16x8*)&As[(wm<<6)+(m<<4)+lr][ko];
      #pragma unroll
      for (int n=0;n<4;++n) bv[n] = *(const s16x8*)&Bs[(wn<<6)+(n<<4)+lr][ko];
      #pragma unroll
      for (int m=0;m<4;++m)
        #pragma unroll
        for (int n=0;n<4;++n)
          acc[m][n] = __builtin_amdgcn_mfma_f32_16x16x32_bf16(av[m], bv[n], acc[m][n], 0,0,0);
    }
  }
  #pragma unroll
  for (int m=0;m<4;++m)
    #pragma unroll
    for (int n=0;n<4;++n)
      #pragma unroll
      for (int r=0;r<4;++r){
        const int R = b*LL + qbase + (wm<<6) + (m<<4) + rr2 + r;
        const int gc = kh*128 + (wn<<6) + (n<<4) + lr;
        size_t o = (size_t)R*CC + gc;
        outs[o] = prevf[o] + acc[m][n][r];
      }
}

// restore borrowed strips (8192 x 2KB) to zero
__global__ void k_restore(char* gbase){
  size_t strip = blockIdx.x;
  char* p = gbase + ((strip >> 9) << 22) + ((strip & 511) << 12) + 2048;
  f32x4 z; z[0]=0.f; z[1]=0.f; z[2]=0.f; z[3]=0.f;
  ((f32x4*)p)[threadIdx.x] = z;
}

extern "C" void kernel_launch(void* const* d_in, const int* in_sizes, int n_in,
                              void* d_out, int out_size, void* d_ws, size_t ws_size,
                              hipStream_t stream)
{
  (void)in_sizes; (void)n_in; (void)out_size; (void)d_ws; (void)ws_size;
  const float* input  = (const float*)d_in[0];
  const float* ck_w   = (const float*)d_in[1];
  const float* ck_b   = (const float*)d_in[2];
  const float* ck_g   = (const float*)d_in[3];
  const float* ck_be  = (const float*)d_in[4];
  const float* ck_m   = (const float*)d_in[5];
  const float* ck_v   = (const float*)d_in[6];
  const float* cq_w   = (const float*)d_in[7];
  const float* cq_b   = (const float*)d_in[8];
  const float* cq_g   = (const float*)d_in[9];
  const float* cq_be  = (const float*)d_in[10];
  const float* cq_m   = (const float*)d_in[11];
  const float* cq_v   = (const float*)d_in[12];
  const float* qW     = (const float*)d_in[13];
  const float* qb     = (const float*)d_in[14];
  const float* kW     = (const float*)d_in[15];
  const float* kb     = (const float*)d_in[16];
  const float* vW     = (const float*)d_in[17];
  const float* vb     = (const float*)d_in[18];

  float* graphs   = (float*)d_out;
  float* g1       = graphs + (size_t)BB*KHn*LL*LL;
  float* outsBase = graphs + (size_t)NLAYER*BB*KHn*LL*LL;
  float* outs0 = outsBase;
  float* outs1 = outsBase + (size_t)MM*CC;

  // scratch arena in g1 (dead before stile L1 writes g1)
  char* RA = (char*)g1;
  float* key_out  = (float*)(RA + 0);          // 16.78 MB
  float* qry_out  = (float*)(RA + 16777216);   // 16.78 MB
  float* q0v      = (float*)(RA + 33554432);   //  8.39 MB (packed per-head)
  float* k0v      = (float*)(RA + 41943040);   //  8.39 MB (packed per-head)
  short* val0_bf  = (short*)(RA + 50331648);   //  8.39 MB
  short* vW_bf    = (short*)(RA + 58720256);   //  1.05 MB
  float* wTk      = (float*)(RA + 59768832);   //  3.15 MB
  float* wTq      = (float*)(RA + 62914560);   //  3.15 MB
  float* partial0 = (float*)(RA + 66060288);   //  0.26 MB (65536 floats)
  float* ck_sc    = (float*)(RA + 66322432);
  float* ck_sh    = (float*)(RA + 66324480);
  float* cq_sc    = (float*)(RA + 66326528);
  float* cq_sh    = (float*)(RA + 66328576);
  // layer-1 q/k (packed) in outs1 region (dead before pv L1 writes it)
  float* q1v = outs1;
  float* k1v = outs1 + (size_t)MM*KHn*HIDn;
  char* gL0 = (char*)d_out;

  k_scaleshift<<<4, 256, 0, stream>>>(ck_b, ck_g, ck_be, ck_m, ck_v,
                                      cq_b, cq_g, cq_be, cq_m, cq_v,
                                      ck_sc, ck_sh, cq_sc, cq_sh);
  k_convwT<<<(3*CC*CC)/256, 256, 0, stream>>>(ck_w, cq_w, wTk, wTq);
  k_cast<<<(NLAYER*CC*CC)/256, 256, 0, stream>>>(vW, vW_bf, NLAYER*CC*CC);

  k_convT<<<dim3(MM/64, CC/64), 256, 0, stream>>>(input, wTk, ck_sc, ck_sh, key_out);
  k_convT<<<dim3(MM/64, CC/64), 256, 0, stream>>>(input, wTq, cq_sc, cq_sh, qry_out);

  // ---- layer 0 ----
  k_linT<1><<<dim3(MM/64, (KHn*HIDn)/64), 256, 0, stream>>>(qry_out, CC, qW, CC, CC,
                                                            qb, q0v, KHn*HIDn);
  k_linT<1><<<dim3(MM/64, (KHn*HIDn)/64), 256, 0, stream>>>(key_out, CC, kW, CC, CC,
                                                            kb, k0v, KHn*HIDn);
  k_gemm<0><<<dim3(MM/128, CC/128), 256, 0, stream>>>(input, CC, vW_bf, CC, CC,
                                                      vb, val0_bf, CC, nullptr);
  // stile writes EVERY byte of graphs L0 (values + zeros) + all partials
  k_stile<0><<<dim3(128, KHn, BB), 256, 0, stream>>>(q0v, k0v, graphs, partial0, nullptr);
  k_pv<0><<<dim3(LL/128, KHn, BB), 256, 0, stream>>>(graphs, val0_bf, gL0, partial0,
                                                     input, outs0);

  // ---- layer 1 ----
  k_gemm<1><<<dim3(MM/128, CC/128), 256, 0, stream>>>(outs0, CC, vW_bf + (size_t)CC*CC, CC, CC,
                                                      vb + CC, nullptr, CC, gL0);
  k_linT<1><<<dim3(MM/64, (KHn*HIDn)/64), 256, 0, stream>>>(qry_out, CC,
                                                            qW + (size_t)KHn*HIDn*CC, CC, CC,
                                                            qb + KHn*HIDn, q1v, KHn*HIDn);
  k_linT<1><<<dim3(MM/64, (KHn*HIDn)/64), 256, 0, stream>>>(key_out, CC,
                                                            kW + (size_t)KHn*HIDn*CC, CC, CC,
                                                            kb + KHn*HIDn, k1v, KHn*HIDn);
  // arena fully dead now -> stile L1 writes every byte of g1 + strip partials
  k_stile<1><<<dim3(128, KHn, BB), 256, 0, stream>>>(q1v, k1v, g1, nullptr, gL0);
  k_pv<1><<<dim3(LL/128, KHn, BB), 256, 0, stream>>>(g1, nullptr, gL0, nullptr,
                                                     outs0, outs1);
  k_restore<<<8192, 128, 0, stream>>>(gL0);
}

// Round 17
// 955.517 us; speedup vs baseline: 2.5055x; 1.3460x over previous
//
#include <hip/hip_runtime.h>
#include <stdint.h>
#include <stddef.h>

#define BB 8
#define LL 1024
#define CC 512
#define KHn 4
#define HIDn 64
#define NLAYER 2
#define MM (BB*LL)

typedef __attribute__((ext_vector_type(4))) float f32x4;
typedef __attribute__((ext_vector_type(8))) short s16x8;
typedef __attribute__((ext_vector_type(4))) short s16x4;

__device__ __forceinline__ short f2bf(float x){
  union { float f; uint32_t u; } v; v.f = x;
  uint32_t r = v.u + 0x7FFFu + ((v.u >> 16) & 1u);
  return (short)(r >> 16);
}

// bf16 strip scratch in graphs-L0 zero triangle (rows<512, cols>=512): strips 0..4095 (val1)
__device__ __forceinline__ short* strip_ptr(char* base, size_t f){
  size_t beta = f << 1;
  size_t strip = beta >> 11;
  return (short*)(base + ((strip >> 9) << 22) + ((strip & 511) << 12) + 2048 + (beta & 2047));
}
// fp32 strips 4096..4223: L1 partial row sums (65536 floats: [(mk*2+half)][1024])
__device__ __forceinline__ float* sums_strip(char* base, size_t i){
  size_t strip = 4096 + (i >> 9);
  return (float*)(base + ((strip >> 9) << 22) + ((strip & 511) << 12) + 2048) + (i & 511);
}

// ---------------- BN fold ----------------
__global__ void k_scaleshift(const float* b1,const float* g1,const float* be1,const float* m1,const float* v1,
                             const float* b2,const float* g2,const float* be2,const float* m2,const float* v2,
                             float* sc1, float* sh1, float* sc2, float* sh2){
  int c = blockIdx.x*256 + threadIdx.x;
  if (c < CC){
    float s = g1[c]*rsqrtf(v1[c]+1e-5f); sc1[c]=s; sh1[c]=(b1[c]-m1[c])*s+be1[c];
  } else if (c < 2*CC){
    int d = c - CC;
    float s = g2[d]*rsqrtf(v2[d]+1e-5f); sc2[d]=s; sh2[d]=(b2[d]-m2[d])*s+be2[d];
  }
}

// conv weights [O][C][3] -> fp32 [3][O][C]
__global__ void k_convwT(const float* __restrict__ wk, const float* __restrict__ wq,
                         float* __restrict__ wTk, float* __restrict__ wTq){
  int idx = blockIdx.x*256 + threadIdx.x;          // over 3*CC*CC
  int seg = idx / (CC*CC);
  int o   = (idx / CC) % CC;
  int c   = idx % CC;
  size_t src = ((size_t)o*CC + c)*3 + seg;
  wTk[idx] = wk[src];
  wTq[idx] = wq[src];
}

__global__ void k_cast(const float* __restrict__ in, short* __restrict__ out, int n){
  int i = blockIdx.x*256 + threadIdx.x;
  if (i < n) out[i] = f2bf(in[i]);
}

// ---------------- FUSED conv towers fp32, swizzled LDS (bank-conflict-free) ----------------
// Computes key_out AND qry_out in one pass (shared A staging).
// Swizzle: element (k, m) stored at col (m + 4*((k>>2)&7)) & 63, pitch 64.
__global__ __launch_bounds__(256,2)
void k_conv2(const float* __restrict__ X,
             const float* __restrict__ WtK, const float* __restrict__ WtQ,
             const float* __restrict__ scK, const float* __restrict__ shK,
             const float* __restrict__ scQ, const float* __restrict__ shQ,
             float* __restrict__ OK, float* __restrict__ OQ)
{
  __shared__ float As[64][64];
  __shared__ float BsK[64][64];
  __shared__ float BsQ[64][64];
  const int tid = threadIdx.x, ty = tid >> 4, tx = tid & 15;
  const int m0 = blockIdx.x << 6, n0 = blockIdx.y << 6;
  const int mlow = m0 & (LL-1);
  float accK[4][4] = {};
  float accQ[4][4] = {};
  for (int seg = 0; seg < 3; ++seg){
    const int shift = seg - 2;
    for (int k0 = 0; k0 < CC; k0 += 64){
      __syncthreads();
      #pragma unroll
      for (int it = 0; it < 4; ++it){
        int idx = tid + (it << 8);
        int r = idx >> 4, c4 = (idx & 15) << 2;
        int colp = (r + ((idx & 7) << 2)) & 63;
        f32x4 av; av[0]=0.f; av[1]=0.f; av[2]=0.f; av[3]=0.f;
        if (mlow + r + shift >= 0) av = *(const f32x4*)&X[(size_t)(m0 + r + shift)*CC + k0 + c4];
        As[c4+0][colp]=av[0]; As[c4+1][colp]=av[1]; As[c4+2][colp]=av[2]; As[c4+3][colp]=av[3];
        f32x4 bk = *(const f32x4*)&WtK[((size_t)seg*CC + n0 + r)*CC + k0 + c4];
        BsK[c4+0][colp]=bk[0]; BsK[c4+1][colp]=bk[1]; BsK[c4+2][colp]=bk[2]; BsK[c4+3][colp]=bk[3];
        f32x4 bq = *(const f32x4*)&WtQ[((size_t)seg*CC + n0 + r)*CC + k0 + c4];
        BsQ[c4+0][colp]=bq[0]; BsQ[c4+1][colp]=bq[1]; BsQ[c4+2][colp]=bq[2]; BsQ[c4+3][colp]=bq[3];
      }
      __syncthreads();
      #pragma unroll
      for (int k = 0; k < 64; ++k){
        const int s4 = ((k >> 2) & 7) << 2;
        f32x4 qa = *(const f32x4*)&As[k][((ty<<2) + s4) & 63];
        f32x4 kk = *(const f32x4*)&BsK[k][((tx<<2) + s4) & 63];
        f32x4 qq = *(const f32x4*)&BsQ[k][((tx<<2) + s4) & 63];
        #pragma unroll
        for (int i=0;i<4;++i)
          #pragma unroll
          for (int j=0;j<4;++j){
            accK[i][j] += qa[i]*kk[j];
            accQ[i][j] += qa[i]*qq[j];
          }
      }
    }
  }
  const int c0 = n0 + (tx<<2);
  f32x4 sK = *(const f32x4*)&scK[c0];
  f32x4 hK = *(const f32x4*)&shK[c0];
  f32x4 sQ = *(const f32x4*)&scQ[c0];
  f32x4 hQ = *(const f32x4*)&shQ[c0];
  #pragma unroll
  for (int i=0;i<4;++i){
    int gr = m0 + (ty<<2) + i;
    f32x4 vK, vQ;
    #pragma unroll
    for (int j=0;j<4;++j){
      vK[j] = fmaxf(accK[i][j]*sK[j] + hK[j], 0.f);
      vQ[j] = fmaxf(accQ[i][j]*sQ[j] + hQ[j], 0.f);
    }
    *(f32x4*)&OK[(size_t)gr*CC + c0] = vK;
    *(f32x4*)&OQ[(size_t)gr*CC + c0] = vQ;
  }
}

// ---------------- NT linear fp32, swizzled LDS; PACK=1 -> per-head layout [mk][L][64] ----------------
template<int PACK>
__global__ __launch_bounds__(256,2)
void k_linT(const float* __restrict__ A, int lda,
            const float* __restrict__ B, int ldb, int K,
            const float* __restrict__ bias,
            float* __restrict__ O, int ldo)
{
  __shared__ float As[64][64];
  __shared__ float Bs[64][64];
  const int tid = threadIdx.x, ty = tid >> 4, tx = tid & 15;
  const int m0 = blockIdx.x << 6, n0 = blockIdx.y << 6;
  float accs[4][4] = {};
  for (int k0 = 0; k0 < K; k0 += 64){
    __syncthreads();
    #pragma unroll
    for (int it = 0; it < 4; ++it){
      int idx = tid + (it << 8);
      int r = idx >> 4, c4 = (idx & 15) << 2;
      int colp = (r + ((idx & 7) << 2)) & 63;
      f32x4 av = *(const f32x4*)&A[(size_t)(m0 + r)*lda + k0 + c4];
      As[c4+0][colp]=av[0]; As[c4+1][colp]=av[1]; As[c4+2][colp]=av[2]; As[c4+3][colp]=av[3];
      f32x4 bv = *(const f32x4*)&B[(size_t)(n0 + r)*ldb + k0 + c4];
      Bs[c4+0][colp]=bv[0]; Bs[c4+1][colp]=bv[1]; Bs[c4+2][colp]=bv[2]; Bs[c4+3][colp]=bv[3];
    }
    __syncthreads();
    #pragma unroll
    for (int k = 0; k < 64; ++k){
      const int s4 = ((k >> 2) & 7) << 2;
      f32x4 qa = *(const f32x4*)&As[k][((ty<<2) + s4) & 63];
      f32x4 kb = *(const f32x4*)&Bs[k][((tx<<2) + s4) & 63];
      #pragma unroll
      for (int i=0;i<4;++i)
        #pragma unroll
        for (int j=0;j<4;++j)
          accs[i][j] += qa[i]*kb[j];
    }
  }
  const int c0 = n0 + (tx<<2);
  f32x4 b4 = *(const f32x4*)&bias[c0];
  #pragma unroll
  for (int i=0;i<4;++i){
    int gr = m0 + (ty<<2) + i;
    f32x4 v;
    #pragma unroll
    for (int j=0;j<4;++j) v[j] = accs[i][j] + b4[j];
    if (PACK){
      int bb = gr >> 10, l = gr & (LL-1);
      int kh = c0 >> 6, h = c0 & 63;
      *(f32x4*)&O[(((size_t)(bb*KHn + kh))*LL + l)*HIDn + h] = v;
    } else {
      *(f32x4*)&O[(size_t)gr*ldo + c0] = v;
    }
  }
}

// ---------------- scores: block = 16 q-rows x 512 s-cols; granule-dense row writes ----------------
// Writes unnormalized relu(qk)^2*mask for ALL (q,s) it owns (incl. zeros for s>=q).
// q/k packed per-head [mk][1024][64]. partial[(mk*2+half)*1024 + q] written exactly once.
template<int SSTRIP>
__global__ __launch_bounds__(256,2)
void k_stile(const float* __restrict__ qp, const float* __restrict__ kp,
             float* __restrict__ gout, float* __restrict__ partial, char* sbase)
{
  __shared__ float Qs[64][20];   // [h][row 0..15]
  __shared__ float Ks[64][64];   // [h][s-local], swizzled
  const int tid = threadIdx.x, lane = tid & 63, w = tid >> 6;
  const int band = blockIdx.x >> 1, half = blockIdx.x & 1;
  const int kh = blockIdx.y, b = blockIdx.z;
  const int q0 = band << 4;          // 16 rows
  const int s0 = half << 9;          // 512 cols
  const int mk = b*KHn + kh;
  float* grow = gout + (size_t)mk*LL*LL;

  const bool compute = (s0 < q0 + 15);
  float acc[4][8];
  #pragma unroll
  for (int i=0;i<4;++i)
    #pragma unroll
    for (int j=0;j<8;++j) acc[i][j] = 0.f;

  if (compute){
    const float* qb = qp + (size_t)mk*LL*HIDn;
    const float* kb = kp + (size_t)mk*LL*HIDn;
    // stage Q band: 16 rows x 64 h, transposed
    {
      int row = tid >> 4, c4 = (tid & 15) << 2;
      f32x4 av = *(const f32x4*)&qb[(size_t)(q0 + row)*HIDn + c4];
      Qs[c4+0][row]=av[0]; Qs[c4+1][row]=av[1]; Qs[c4+2][row]=av[2]; Qs[c4+3][row]=av[3];
    }
    for (int j = 0; j < 8; ++j){
      __syncthreads();
      {
        int idx = tid;
        int r = idx >> 4, c4 = (idx & 15) << 2;
        int sw = (idx & 7) << 2;
        #pragma unroll
        for (int it = 0; it < 4; ++it){
          int rr = r + (it << 4);
          int colp = (rr + sw) & 63;
          f32x4 bv = *(const f32x4*)&kb[(size_t)(s0 + (j<<6) + rr)*HIDn + c4];
          Ks[c4+0][colp]=bv[0]; Ks[c4+1][colp]=bv[1]; Ks[c4+2][colp]=bv[2]; Ks[c4+3][colp]=bv[3];
        }
      }
      __syncthreads();
      #pragma unroll
      for (int h = 0; h < 64; ++h){
        float kv = Ks[h][(lane + (((h >> 2) & 7) << 2)) & 63];
        #pragma unroll
        for (int i=0;i<4;++i)
          acc[i][j] += Qs[h][(w<<2)+i] * kv;
      }
    }
  }
  // write phase: per row, 8 back-to-back 256B stores = dense 2KB granules
  #pragma unroll
  for (int i=0;i<4;++i){
    const int q = q0 + (w<<2) + i;
    float psum = 0.f;
    float* rw = &grow[(size_t)q*LL + s0];
    #pragma unroll
    for (int j=0;j<8;++j){
      const int s = s0 + (j<<6) + lane;
      float tt = (compute && s < q) ? fmaxf(acc[i][j], 0.f) : 0.f;
      float v = tt*tt;
      psum += v;
      rw[(j<<6) + lane] = v;
    }
    psum += __shfl_xor(psum, 1);  psum += __shfl_xor(psum, 2);
    psum += __shfl_xor(psum, 4);  psum += __shfl_xor(psum, 8);
    psum += __shfl_xor(psum, 16); psum += __shfl_xor(psum, 32);
    if (lane == 0){
      size_t idx = (((size_t)mk*2 + half) << 10) + q;
      if (SSTRIP) *sums_strip(sbase, idx) = psum;
      else        partial[idx] = psum;
    }
  }
}

// ---------------- MFMA GEMM (v-proj): val = bf16(A_f32 @ B_bf16^T + bias) ----------------
template<int SOUT>
__global__ __launch_bounds__(256,2)
void k_gemm(const float* __restrict__ Af, int lda,
            const short* __restrict__ Bm, int ldb, int K,
            const float* __restrict__ bias,
            short* __restrict__ Obf, int ldo, char* gbase)
{
  __shared__ short As[128][72];
  __shared__ short Bs[128][72];
  const int tid = threadIdx.x, lane = tid & 63, wid = tid >> 6;
  const int wm = wid >> 1, wn = wid & 1;
  const int m0 = blockIdx.x << 7, n0 = blockIdx.y << 7;
  const int lr = lane & 15, lk = (lane >> 4) << 3;

  f32x4 acc[4][4];
  #pragma unroll
  for (int m=0;m<4;++m)
    #pragma unroll
    for (int n=0;n<4;++n){ acc[m][n][0]=0.f; acc[m][n][1]=0.f; acc[m][n][2]=0.f; acc[m][n][3]=0.f; }

  for (int k0 = 0; k0 < K; k0 += 64){
    __syncthreads();
    #pragma unroll
    for (int it=0; it<4; ++it){
      int idx8 = tid + (it<<8);
      int r = idx8 >> 3, cv = (idx8 & 7) << 3;
      f32x4 v0 = *(const f32x4*)&Af[(size_t)(m0+r)*lda + k0 + cv];
      f32x4 v1 = *(const f32x4*)&Af[(size_t)(m0+r)*lda + k0 + cv + 4];
      s16x8 h;
      h[0]=f2bf(v0[0]); h[1]=f2bf(v0[1]); h[2]=f2bf(v0[2]); h[3]=f2bf(v0[3]);
      h[4]=f2bf(v1[0]); h[5]=f2bf(v1[1]); h[6]=f2bf(v1[2]); h[7]=f2bf(v1[3]);
      *(s16x8*)&As[r][cv] = h;
      *(s16x8*)&Bs[r][cv] = *(const s16x8*)&Bm[(size_t)(n0+r)*ldb + k0 + cv];
    }
    __syncthreads();
    #pragma unroll
    for (int kj=0; kj<2; ++kj){
      const int ko = (kj<<5) + lk;
      s16x8 av[4], bv[4];
      #pragma unroll
      for (int m=0;m<4;++m) av[m] = *(const s16x8*)&As[(wm<<6) + (m<<4) + lr][ko];
      #pragma unroll
      for (int n=0;n<4;++n) bv[n] = *(const s16x8*)&Bs[(wn<<6) + (n<<4) + lr][ko];
      #pragma unroll
      for (int m=0;m<4;++m)
        #pragma unroll
        for (int n=0;n<4;++n)
          acc[m][n] = __builtin_amdgcn_mfma_f32_16x16x32_bf16(av[m], bv[n], acc[m][n], 0,0,0);
    }
  }
  const int rr = (lane >> 4) << 2;
  #pragma unroll
  for (int m=0;m<4;++m)
    #pragma unroll
    for (int n=0;n<4;++n){
      const int gc = n0 + (wn<<6) + (n<<4) + lr;
      float e0 = bias[gc];
      #pragma unroll
      for (int r=0;r<4;++r){
        const int gr = m0 + (wm<<6) + (m<<4) + rr + r;
        short val = f2bf(acc[m][n][r] + e0);
        if (SOUT) *strip_ptr(gbase, (size_t)gr*ldo + gc) = val;
        else      Obf[(size_t)gr*ldo + gc] = val;
      }
    }
}

// ---------------- MFMA PV: fused 2-way sum-reduce + normalize + write-back ----------------
template<int VS>
__global__ __launch_bounds__(256,2)
void k_pv(float* __restrict__ att, const short* __restrict__ valbf, char* vbase,
          const float* __restrict__ partial,
          const float* __restrict__ prevf, float* __restrict__ outs)
{
  __shared__ short As[128][72];
  __shared__ short Bs[128][72];
  __shared__ float rinv_s[128];
  const int tid = threadIdx.x, lane = tid & 63, wid = tid >> 6;
  const int wm = wid >> 1, wn = wid & 1;
  const int qt = blockIdx.x, kh = blockIdx.y, b = blockIdx.z;
  const int qbase = qt << 7;
  const int lr = lane & 15, lk = (lane >> 4) << 3, rr2 = (lane >> 4) << 2;
  const int mk = b*KHn + kh;
  float* attb = att + ((size_t)mk)*LL*LL;

  if (tid < 128){
    int q = qbase + tid;
    float s = 0.f;
    #pragma unroll
    for (int g = 0; g < 2; ++g){
      size_t idx = (((size_t)mk*2 + g) << 10) + q;
      s += VS ? *sums_strip(vbase, idx) : partial[idx];
    }
    rinv_s[tid] = 1.0f/(s + 1e-16f);
  }

  f32x4 acc[4][4];
  #pragma unroll
  for (int m=0;m<4;++m)
    #pragma unroll
    for (int n=0;n<4;++n){ acc[m][n][0]=0.f; acc[m][n][1]=0.f; acc[m][n][2]=0.f; acc[m][n][3]=0.f; }

  const int nt = (qbase >> 6) + 2;
  for (int st=0; st<nt; ++st){
    const int sb = st << 6;
    __syncthreads();
    #pragma unroll
    for (int it=0; it<8; ++it){
      int idx4 = tid + (it<<8);
      int r = idx4 >> 4, cv = (idx4 & 15) << 2;
      float* src = &attb[(size_t)(qbase + r)*LL + sb + cv];
      f32x4 v = *(f32x4*)src;
      float ri = rinv_s[r];
      v[0]*=ri; v[1]*=ri; v[2]*=ri; v[3]*=ri;
      *(f32x4*)src = v;
      s16x4 h; h[0]=f2bf(v[0]); h[1]=f2bf(v[1]); h[2]=f2bf(v[2]); h[3]=f2bf(v[3]);
      *(s16x4*)&As[r][cv] = h;
    }
    #pragma unroll
    for (int it=0; it<32; ++it){
      int idx = tid + (it<<8);
      int sl = idx >> 7, d = idx & 127;
      size_t f = (size_t)(b*LL + sb + sl)*CC + kh*128 + d;
      Bs[d][sl] = VS ? *strip_ptr(vbase, f) : valbf[f];
    }
    __syncthreads();
    #pragma unroll
    for (int kj=0;kj<2;++kj){
      int ko = (kj<<5) + lk;
      s16x8 av[4], bv[4];
      #pragma unroll
      for (int m=0;m<4;++m) av[m] = *(const s16x8*)&As[(wm<<6)+(m<<4)+lr][ko];
      #pragma unroll
      for (int n=0;n<4;++n) bv[n] = *(const s16x8*)&Bs[(wn<<6)+(n<<4)+lr][ko];
      #pragma unroll
      for (int m=0;m<4;++m)
        #pragma unroll
        for (int n=0;n<4;++n)
          acc[m][n] = __builtin_amdgcn_mfma_f32_16x16x32_bf16(av[m], bv[n], acc[m][n], 0,0,0);
    }
  }
  #pragma unroll
  for (int m=0;m<4;++m)
    #pragma unroll
    for (int n=0;n<4;++n)
      #pragma unroll
      for (int r=0;r<4;++r){
        const int R = b*LL + qbase + (wm<<6) + (m<<4) + rr2 + r;
        const int gc = kh*128 + (wn<<6) + (n<<4) + lr;
        size_t o = (size_t)R*CC + gc;
        outs[o] = prevf[o] + acc[m][n][r];
      }
}

// restore borrowed strips (8192 x 2KB) to zero
__global__ void k_restore(char* gbase){
  size_t strip = blockIdx.x;
  char* p = gbase + ((strip >> 9) << 22) + ((strip & 511) << 12) + 2048;
  f32x4 z; z[0]=0.f; z[1]=0.f; z[2]=0.f; z[3]=0.f;
  ((f32x4*)p)[threadIdx.x] = z;
}

extern "C" void kernel_launch(void* const* d_in, const int* in_sizes, int n_in,
                              void* d_out, int out_size, void* d_ws, size_t ws_size,
                              hipStream_t stream)
{
  (void)in_sizes; (void)n_in; (void)out_size; (void)d_ws; (void)ws_size;
  const float* input  = (const float*)d_in[0];
  const float* ck_w   = (const float*)d_in[1];
  const float* ck_b   = (const float*)d_in[2];
  const float* ck_g   = (const float*)d_in[3];
  const float* ck_be  = (const float*)d_in[4];
  const float* ck_m   = (const float*)d_in[5];
  const float* ck_v   = (const float*)d_in[6];
  const float* cq_w   = (const float*)d_in[7];
  const float* cq_b   = (const float*)d_in[8];
  const float* cq_g   = (const float*)d_in[9];
  const float* cq_be  = (const float*)d_in[10];
  const float* cq_m   = (const float*)d_in[11];
  const float* cq_v   = (const float*)d_in[12];
  const float* qW     = (const float*)d_in[13];
  const float* qb     = (const float*)d_in[14];
  const float* kW     = (const float*)d_in[15];
  const float* kb     = (const float*)d_in[16];
  const float* vW     = (const float*)d_in[17];
  const float* vb     = (const float*)d_in[18];

  float* graphs   = (float*)d_out;
  float* g1       = graphs + (size_t)BB*KHn*LL*LL;
  float* outsBase = graphs + (size_t)NLAYER*BB*KHn*LL*LL;
  float* outs0 = outsBase;
  float* outs1 = outsBase + (size_t)MM*CC;

  // scratch arena in g1 (dead before stile L1 writes g1)
  char* RA = (char*)g1;
  float* key_out  = (float*)(RA + 0);          // 16.78 MB
  float* qry_out  = (float*)(RA + 16777216);   // 16.78 MB
  float* q0v      = (float*)(RA + 33554432);   //  8.39 MB (packed per-head)
  float* k0v      = (float*)(RA + 41943040);   //  8.39 MB (packed per-head)
  short* val0_bf  = (short*)(RA + 50331648);   //  8.39 MB
  short* vW_bf    = (short*)(RA + 58720256);   //  1.05 MB
  float* wTk      = (float*)(RA + 59768832);   //  3.15 MB
  float* wTq      = (float*)(RA + 62914560);   //  3.15 MB
  float* partial0 = (float*)(RA + 66060288);   //  0.26 MB (65536 floats)
  float* ck_sc    = (float*)(RA + 66322432);
  float* ck_sh    = (float*)(RA + 66324480);
  float* cq_sc    = (float*)(RA + 66326528);
  float* cq_sh    = (float*)(RA + 66328576);
  // layer-1 q/k (packed) in outs1 region (dead before pv L1 writes it)
  float* q1v = outs1;
  float* k1v = outs1 + (size_t)MM*KHn*HIDn;
  char* gL0 = (char*)d_out;

  k_scaleshift<<<4, 256, 0, stream>>>(ck_b, ck_g, ck_be, ck_m, ck_v,
                                      cq_b, cq_g, cq_be, cq_m, cq_v,
                                      ck_sc, ck_sh, cq_sc, cq_sh);
  k_convwT<<<(3*CC*CC)/256, 256, 0, stream>>>(ck_w, cq_w, wTk, wTq);
  k_cast<<<(NLAYER*CC*CC)/256, 256, 0, stream>>>(vW, vW_bf, NLAYER*CC*CC);

  // fused conv towers (shared A staging, swizzled LDS)
  k_conv2<<<dim3(MM/64, CC/64), 256, 0, stream>>>(input, wTk, wTq,
                                                  ck_sc, ck_sh, cq_sc, cq_sh,
                                                  key_out, qry_out);

  // ---- layer 0 ----
  k_linT<1><<<dim3(MM/64, (KHn*HIDn)/64), 256, 0, stream>>>(qry_out, CC, qW, CC, CC,
                                                            qb, q0v, KHn*HIDn);
  k_linT<1><<<dim3(MM/64, (KHn*HIDn)/64), 256, 0, stream>>>(key_out, CC, kW, CC, CC,
                                                            kb, k0v, KHn*HIDn);
  k_gemm<0><<<dim3(MM/128, CC/128), 256, 0, stream>>>(input, CC, vW_bf, CC, CC,
                                                      vb, val0_bf, CC, nullptr);
  // stile writes EVERY byte of graphs L0 (values + zeros) + all partials
  k_stile<0><<<dim3(128, KHn, BB), 256, 0, stream>>>(q0v, k0v, graphs, partial0, nullptr);
  k_pv<0><<<dim3(LL/128, KHn, BB), 256, 0, stream>>>(graphs, val0_bf, gL0, partial0,
                                                     input, outs0);

  // ---- layer 1 ----
  k_gemm<1><<<dim3(MM/128, CC/128), 256, 0, stream>>>(outs0, CC, vW_bf + (size_t)CC*CC, CC, CC,
                                                      vb + CC, nullptr, CC, gL0);
  k_linT<1><<<dim3(MM/64, (KHn*HIDn)/64), 256, 0, stream>>>(qry_out, CC,
                                                            qW + (size_t)KHn*HIDn*CC, CC, CC,
                                                            qb + KHn*HIDn, q1v, KHn*HIDn);
  k_linT<1><<<dim3(MM/64, (KHn*HIDn)/64), 256, 0, stream>>>(key_out, CC,
                                                            kW + (size_t)KHn*HIDn*CC, CC, CC,
                                                            kb + KHn*HIDn, k1v, KHn*HIDn);
  // arena fully dead now -> stile L1 writes every byte of g1 + strip partials
  k_stile<1><<<dim3(128, KHn, BB), 256, 0, stream>>>(q1v, k1v, g1, nullptr, gL0);
  k_pv<1><<<dim3(LL/128, KHn, BB), 256, 0, stream>>>(g1, nullptr, gL0, nullptr,
                                                     outs0, outs1);
  k_restore<<<8192, 128, 0, stream>>>(gL0);
}